// Round 2
// baseline (43.952 us; speedup 1.0000x reference)
//
#include <hip/hip_runtime.h>

// Problem constants (fixed by the reference setup_inputs): B=2048, C=2704, D=5
#define N_CELLS (2048 * 2704)            // 5,537,792 cells
#define N_ELEMS (N_CELLS * 5)            // 27,688,960 floats per array
#define N_F4    (N_ELEMS / 4)            // 6,922,240 float4s (exact)
#define RBLOCKS 2048
#define RTHREADS 256
#define GSTRIDE (RBLOCKS * RTHREADS)     // 524,288 threads
#define NITER   ((N_F4 + GSTRIDE - 1) / GSTRIDE)   // 14 iterations
#define LOG_CLAMP (-100.0f)

// Pass 1: fully-coalesced float4 streaming. Each lane handles one float4 (4
// elements) per iteration. Channel structure (period 5) is resolved per-lane:
//   - element e is the confidence channel iff e % 5 == 0
//   - a lane's float4 [4T .. 4T+3] contains at most ONE conf element, at
//     component j == T % 5 (when T%5 < 4)
//   - a box element's cell-confidence lives at element 5*(e/5) in [e-4, e-1],
//     i.e. in THIS lane's float4 or the PREVIOUS lane's -> one __shfl_up,
//     lane 0 patched by a predicated scalar load (covers wave/block seams).
__global__ __launch_bounds__(RTHREADS) void mloss_partial(
    const float4* __restrict__ x4, const float4* __restrict__ y4,
    const float* __restrict__ yflat, float* __restrict__ ws) {
  float cnt = 0.f, sbox = 0.f, sbce = 0.f, sbg = 0.f;
  const int tid = blockIdx.x * RTHREADS + threadIdx.x;
  const int lane = threadIdx.x & 63;

  for (int it = 0; it < NITER; ++it) {
    const unsigned T = (unsigned)tid + (unsigned)it * GSTRIDE;
    const bool act = T < (unsigned)N_F4;

    float4 xv, yv;
    if (act) {
      xv = x4[T];
      yv = y4[T];
    } else {
      xv = make_float4(0.5f, 0.f, 0.f, 0.f);
      yv = make_float4(0.f, 0.f, 0.f, 0.f);
    }

    const unsigned e0 = 4u * T;
    const unsigned r  = T % 5u;                 // conf component index if < 4
    const bool has_conf = (r < 4u);
    // r0 = e0 % 5  (residue of first element): r->r0 = (5-r)%5
    const unsigned r0 = (r == 0u) ? 0u : (5u - r);

    // extract the conf (t, c) pair from this lane's float4 (cndmask chain)
    float tconf = (r == 0u) ? yv.x : (r == 1u) ? yv.y : (r == 2u) ? yv.z : yv.w;
    float cconf = (r == 0u) ? xv.x : (r == 1u) ? xv.y : (r == 2u) ? xv.z : xv.w;
    if (!has_conf) { tconf = 0.f; cconf = 0.5f; }   // keep logs finite

    const float m_own_f = (tconf > 0.5f) ? 1.f : 0.f;

    // mask of the preceding cell: previous lane's conf
    float m_prev_f = __shfl_up(m_own_f, 1);
    if (lane == 0 && act && r0 != 0u) {
      // this float4 doesn't start at a cell boundary: fetch cell-0 conf direct
      m_prev_f = (yflat[e0 - r0] > 0.5f) ? 1.f : 0.f;
    }

    // BCE / cnt / bg contributions of this lane's conf element
    {
      float lc  = fmaxf(__logf(cconf), LOG_CLAMP);
      float l1c = fmaxf(__logf(1.f - cconf), LOG_CLAMP);
      float bce = -(tconf * lc + (1.f - tconf) * l1c);
      float g = (act && has_conf) ? 1.f : 0.f;
      cnt  += g * m_own_f;
      sbce += g * m_own_f * bce;
      sbg  += g * (1.f - m_own_f) * (-l1c);
    }

    // box contributions of the (up to 4) non-conf components
    const float xa[4] = {xv.x, xv.y, xv.z, xv.w};
    const float ya[4] = {yv.x, yv.y, yv.z, yv.w};
#pragma unroll
    for (int j = 0; j < 4; ++j) {
      // element e0+j belongs to cell c; its conf is in this lane iff the cell
      // starts at/after e0:  (r0==0) || (r0+j >= 5)
      const bool is_own = (r0 == 0u) | ((r0 + (unsigned)j) >= 5u);
      float mask = is_own ? m_own_f : m_prev_f;
      float isbox = (act && ((unsigned)j != r)) ? 1.f : 0.f;
      float d = xa[j] - ya[j];
      sbox += isbox * mask * d * d;
    }
  }

  // wave (64-lane) reduce
#pragma unroll
  for (int off = 32; off; off >>= 1) {
    cnt  += __shfl_down(cnt, off);
    sbox += __shfl_down(sbox, off);
    sbce += __shfl_down(sbce, off);
    sbg  += __shfl_down(sbg, off);
  }

  __shared__ float red[4][4];
  int wave = threadIdx.x >> 6;
  if ((threadIdx.x & 63) == 0) {
    red[wave][0] = cnt; red[wave][1] = sbox;
    red[wave][2] = sbce; red[wave][3] = sbg;
  }
  __syncthreads();
  if (threadIdx.x == 0) {
    float r0s = 0.f, r1s = 0.f, r2s = 0.f, r3s = 0.f;
#pragma unroll
    for (int w = 0; w < 4; ++w) {
      r0s += red[w][0]; r1s += red[w][1]; r2s += red[w][2]; r3s += red[w][3];
    }
    float* o = ws + (size_t)blockIdx.x * 4;
    o[0] = r0s; o[1] = r1s; o[2] = r2s; o[3] = r3s;
  }
}

// Pass 2: one block deterministically reduces the 2048 block partials and
// applies the final loss formula.
__global__ __launch_bounds__(RTHREADS) void mloss_final(
    const float* __restrict__ ws, float* __restrict__ out) {
  float r0 = 0.f, r1 = 0.f, r2 = 0.f, r3 = 0.f;
  for (int i = threadIdx.x; i < RBLOCKS; i += RTHREADS) {
    const float* p = ws + (size_t)i * 4;
    r0 += p[0]; r1 += p[1]; r2 += p[2]; r3 += p[3];
  }
#pragma unroll
  for (int off = 32; off; off >>= 1) {
    r0 += __shfl_down(r0, off);
    r1 += __shfl_down(r1, off);
    r2 += __shfl_down(r2, off);
    r3 += __shfl_down(r3, off);
  }
  __shared__ float red[4][4];
  int wave = threadIdx.x >> 6;
  if ((threadIdx.x & 63) == 0) {
    red[wave][0] = r0; red[wave][1] = r1;
    red[wave][2] = r2; red[wave][3] = r3;
  }
  __syncthreads();
  if (threadIdx.x == 0) {
    float cnt = 0.f, sbox = 0.f, sbce = 0.f, sbg = 0.f;
#pragma unroll
    for (int w = 0; w < 4; ++w) {
      cnt += red[w][0]; sbox += red[w][1]; sbce += red[w][2]; sbg += red[w][3];
    }
    float face_num = cnt;
    float bg_num = (float)N_CELLS - cnt;
    float scale = 1.f + 1.f / face_num;
    out[0] = scale * (sbox / (4.f * face_num) + sbce / face_num) + sbg / bg_num;
  }
}

extern "C" void kernel_launch(void* const* d_in, const int* in_sizes, int n_in,
                              void* d_out, int out_size, void* d_ws, size_t ws_size,
                              hipStream_t stream) {
  const float* x = (const float*)d_in[0];
  const float* y = (const float*)d_in[1];
  float* ws = (float*)d_ws;          // needs RBLOCKS*4*4 = 32 KiB
  float* out = (float*)d_out;

  mloss_partial<<<RBLOCKS, RTHREADS, 0, stream>>>(
      (const float4*)x, (const float4*)y, y, ws);
  mloss_final<<<1, RTHREADS, 0, stream>>>(ws, out);
}